// Round 3
// baseline (100.793 us; speedup 1.0000x reference)
//
#include <hip/hip_runtime.h>
#include <stdint.h>

namespace {

constexpr int kB = 32, kS = 8, kT = 1024, kF = 128;
constexpr int kBS = kB * kS;          // 256
constexpr int kSlice = kT * kF;       // 131072 elements per (b,s)
constexpr uint32_t kSpanT = 122;      // randint(1, 123) span
constexpr uint32_t kSpanF = 15;       // randint(1, 16)  span

typedef float f32x4 __attribute__((ext_vector_type(4)));

struct BSParams {
  int ts1, te1, ts2, te2;   // time-mask intervals [s,e) (apply folded: e==s when not applied)
  int fs1, fe1, fs2, fe2;   // freq-mask intervals
  float scale;
  int apply_n;
  uint32_t kn0, kn1;        // noise key
};  // 48 bytes

__device__ __forceinline__ uint32_t rotl32(uint32_t v, int d) {
  return (v << d) | (v >> (32 - d));
}

// Threefry-2x32, 20 rounds (JAX-compatible).
__device__ __forceinline__ void tf2x32(uint32_t k0, uint32_t k1, uint32_t x0, uint32_t x1,
                                       uint32_t& o0, uint32_t& o1) {
  const uint32_t ks0 = k0, ks1 = k1, ks2 = k0 ^ k1 ^ 0x1BD11BDAu;
  x0 += ks0; x1 += ks1;
  x0 += x1; x1 = rotl32(x1, 13); x1 ^= x0;
  x0 += x1; x1 = rotl32(x1, 15); x1 ^= x0;
  x0 += x1; x1 = rotl32(x1, 26); x1 ^= x0;
  x0 += x1; x1 = rotl32(x1, 6);  x1 ^= x0;
  x0 += ks1; x1 += ks2 + 1u;
  x0 += x1; x1 = rotl32(x1, 17); x1 ^= x0;
  x0 += x1; x1 = rotl32(x1, 29); x1 ^= x0;
  x0 += x1; x1 = rotl32(x1, 16); x1 ^= x0;
  x0 += x1; x1 = rotl32(x1, 24); x1 ^= x0;
  x0 += ks2; x1 += ks0 + 2u;
  x0 += x1; x1 = rotl32(x1, 13); x1 ^= x0;
  x0 += x1; x1 = rotl32(x1, 15); x1 ^= x0;
  x0 += x1; x1 = rotl32(x1, 26); x1 ^= x0;
  x0 += x1; x1 = rotl32(x1, 6);  x1 ^= x0;
  x0 += ks0; x1 += ks1 + 3u;
  x0 += x1; x1 = rotl32(x1, 17); x1 ^= x0;
  x0 += x1; x1 = rotl32(x1, 29); x1 ^= x0;
  x0 += x1; x1 = rotl32(x1, 16); x1 ^= x0;
  x0 += x1; x1 = rotl32(x1, 24); x1 ^= x0;
  x0 += ks1; x1 += ks2 + 4u;
  x0 += x1; x1 = rotl32(x1, 13); x1 ^= x0;
  x0 += x1; x1 = rotl32(x1, 15); x1 ^= x0;
  x0 += x1; x1 = rotl32(x1, 26); x1 ^= x0;
  x0 += x1; x1 = rotl32(x1, 6);  x1 ^= x0;
  x0 += ks2; x1 += ks0 + 5u;
  o0 = x0; o1 = x1;
}

// Partitionable-mode random bits (32-bit) at flat counter i: xor of both output words.
__device__ __forceinline__ uint32_t bits32(uint32_t k0, uint32_t k1, uint32_t ctr) {
  uint32_t o0, o1;
  tf2x32(k0, k1, 0u, ctr, o0, o1);
  return o0 ^ o1;
}

// uniform [0,1) from 32 random bits, JAX-style.
__device__ __forceinline__ float u01(uint32_t bits) {
  return __uint_as_float(0x3f800000u | (bits >> 9)) - 1.0f;
}

// Fast erfinv: Giles main poly with hardware log, branchless 2-term tail.
// Tail fit err <= 0.011 over w in [5,16.6] -> <=0.001 on the final output (budget 0.113).
__device__ __forceinline__ float erfinv_fast(float x) {
  float t = fmaf(-x, x, 1.0f);                          // 1 - x^2 (fma: no cancellation)
  float w = -0.69314718f * __builtin_amdgcn_logf(t);    // -ln(1-x^2)
  float wm = w - 2.5f;
  float p = 2.81022636e-08f;
  p = fmaf(p, wm, 3.43273939e-07f);
  p = fmaf(p, wm, -3.5233877e-06f);
  p = fmaf(p, wm, -4.39150654e-06f);
  p = fmaf(p, wm, 0.00021858087f);
  p = fmaf(p, wm, -0.00125372503f);
  p = fmaf(p, wm, -0.00417768164f);
  p = fmaf(p, wm, 0.246640727f);
  p = fmaf(p, wm, 1.50140941f);
  float tail = fmaf(1.0003f, __builtin_amdgcn_sqrtf(w), -0.1623f);
  p = (w < 5.0f) ? p : tail;
  return p * x;
}

// One _axis_mask's per-(b,s) params: split(K,3) -> k1(randint),k2(uniform start),k3(apply).
__device__ void axis_params(uint32_t K0, uint32_t K1, int dim, uint32_t span, uint32_t i,
                            int& start_out, int& end_out) {
  uint32_t k10, k11, k20, k21, k30, k31, a0, a1, b0, b1;
  tf2x32(K0, K1, 0u, 0u, k10, k11);   // k1
  tf2x32(K0, K1, 0u, 1u, k20, k21);   // k2
  tf2x32(K0, K1, 0u, 2u, k30, k31);   // k3
  tf2x32(k10, k11, 0u, 0u, a0, a1);   // randint internal split
  tf2x32(k10, k11, 0u, 1u, b0, b1);
  uint32_t hi = bits32(a0, a1, i);
  uint32_t lo = bits32(b0, b1, i);
  uint32_t mult = 65536u % span;
  mult = (mult * mult) % span;
  uint32_t off = ((hi % span) * mult + (lo % span)) % span;
  int width = 1 + (int)off;
  float u = u01(bits32(k20, k21, i));
  int M = dim - width; if (M < 1) M = 1;
  int start = (int)floorf(u * (float)M);
  bool apply = u01(bits32(k30, k31, i)) > 0.35f;
  start_out = start;
  end_out = apply ? (start + width) : start;   // empty interval when not applied
}

__device__ BSParams compute_params(uint32_t i) {
  BSParams p;
  uint32_t w0, w1;
  tf2x32(0u, 42u, 0u, 0u, w0, w1); axis_params(w0, w1, kT, kSpanT, i, p.ts1, p.te1);  // kt1
  tf2x32(0u, 42u, 0u, 1u, w0, w1); axis_params(w0, w1, kT, kSpanT, i, p.ts2, p.te2);  // kt2
  tf2x32(0u, 42u, 0u, 2u, w0, w1); axis_params(w0, w1, kF, kSpanF, i, p.fs1, p.fe1);  // kf1
  tf2x32(0u, 42u, 0u, 3u, w0, w1); axis_params(w0, w1, kF, kSpanF, i, p.fs2, p.fe2);  // kf2
  tf2x32(0u, 42u, 0u, 4u, w0, w1);                                                    // kn_a
  p.apply_n = (u01(bits32(w0, w1, i)) > 0.45f) ? 1 : 0;
  tf2x32(0u, 42u, 0u, 5u, p.kn0, p.kn1);                                              // kn
  tf2x32(0u, 42u, 0u, 6u, w0, w1);                                                    // ks_a
  bool apply_s = u01(bits32(w0, w1, i)) > 0.5f;
  tf2x32(0u, 42u, 0u, 7u, w0, w1);                                                    // ks
  float su = u01(bits32(w0, w1, i));
  float sc = fmaxf(0.85f, fmaf(su, 1.15f - 0.85f, 0.85f));
  p.scale = apply_s ? sc : 1.0f;
  return p;
}

__global__ void spec_params_kernel(BSParams* __restrict__ P) {
  uint32_t i = threadIdx.x;  // 0..255 == b*8+s
  P[i] = compute_params(i);
}

template <bool USE_WS>
__global__ __launch_bounds__(256) void spec_main_kernel(const float* __restrict__ specs,
                                                        const int* __restrict__ mask,
                                                        float* __restrict__ out,
                                                        const BSParams* __restrict__ P) {
  const int bs = blockIdx.y;                            // 0..255
  const int off = blockIdx.x * 4096 + threadIdx.x * 16; // element offset within slice
  const long base = (long)bs * kSlice + off;
  const f32x4* in4 = reinterpret_cast<const f32x4*>(specs + base);
  f32x4 a0 = in4[0], a1 = in4[1], a2 = in4[2], a3 = in4[3];
  f32x4* out4 = reinterpret_cast<f32x4*>(out + base);

  if (mask[bs] == 0) {  // sensor off: pure passthrough (uniform per block)
    __builtin_nontemporal_store(a0, &out4[0]);
    __builtin_nontemporal_store(a1, &out4[1]);
    __builtin_nontemporal_store(a2, &out4[2]);
    __builtin_nontemporal_store(a3, &out4[3]);
    return;
  }

  BSParams p;
  if (USE_WS) p = P[bs]; else p = compute_params((uint32_t)bs);

  const int t = off >> 7;        // all 16 elems share t (16 | 128)
  const int f0 = off & 127;      // 0,16,...,112
  const bool tm = !((t >= p.ts1) & (t < p.te1)) && !((t >= p.ts2) & (t < p.te2));

  // 16-bit keep-mask over f in [f0, f0+16)
  int lo1 = min(16, max(0, p.fs1 - f0)), hi1 = min(16, max(0, p.fe1 - f0));
  int lo2 = min(16, max(0, p.fs2 - f0)), hi2 = min(16, max(0, p.fe2 - f0));
  uint32_t z1 = ((1u << hi1) - 1u) & ~((1u << lo1) - 1u);
  uint32_t z2 = ((1u << hi2) - 1u) & ~((1u << lo2) - 1u);
  const uint32_t keep = tm ? (0xFFFFu & ~(z1 | z2)) : 0u;

  float v[16] = {a0.x, a0.y, a0.z, a0.w, a1.x, a1.y, a1.z, a1.w,
                 a2.x, a2.y, a2.z, a2.w, a3.x, a3.y, a3.z, a3.w};

  const float LO = __int_as_float(0xBF7FFFFF);   // nextafter(-1, 0)
  const float sc = p.scale;

  if (p.apply_n) {   // uniform per block
    const uint32_t c0 = (uint32_t)base;
#pragma unroll
    for (int j = 0; j < 16; ++j) {
      float s = (keep & (1u << j)) ? v[j] : 0.0f;
      const uint32_t bits = bits32(p.kn0, p.kn1, c0 + (uint32_t)j);
      float u1 = __uint_as_float(0x3f800000u | (bits >> 9));   // [1,2)
      float x = fmaxf(LO, fmaf(u1, 2.0f, -2.0f) + LO);         // == (u1-1)*2 + LO
      s = fmaf(0.08485281374f, erfinv_fast(x), s);             // 0.06*sqrt(2)*erfinv
      s *= sc;
      v[j] = fminf(10.0f, fmaxf(-10.0f, s));
    }
  } else {
#pragma unroll
    for (int j = 0; j < 16; ++j) {
      float s = (keep & (1u << j)) ? v[j] : 0.0f;
      s *= sc;
      v[j] = fminf(10.0f, fmaxf(-10.0f, s));
    }
  }

  f32x4 r0 = {v[0], v[1], v[2], v[3]};
  f32x4 r1 = {v[4], v[5], v[6], v[7]};
  f32x4 r2 = {v[8], v[9], v[10], v[11]};
  f32x4 r3 = {v[12], v[13], v[14], v[15]};
  __builtin_nontemporal_store(r0, &out4[0]);
  __builtin_nontemporal_store(r1, &out4[1]);
  __builtin_nontemporal_store(r2, &out4[2]);
  __builtin_nontemporal_store(r3, &out4[3]);
}

}  // namespace

extern "C" void kernel_launch(void* const* d_in, const int* in_sizes, int n_in,
                              void* d_out, int out_size, void* d_ws, size_t ws_size,
                              hipStream_t stream) {
  const float* specs = (const float*)d_in[0];
  const int* mask = (const int*)d_in[1];
  float* out = (float*)d_out;

  dim3 grid(kSlice / 4096, kBS);  // (32, 256)
  dim3 block(256);

  if (ws_size >= sizeof(BSParams) * kBS) {
    BSParams* P = (BSParams*)d_ws;
    hipLaunchKernelGGL(spec_params_kernel, dim3(1), dim3(kBS), 0, stream, P);
    hipLaunchKernelGGL((spec_main_kernel<true>), grid, block, 0, stream, specs, mask, out, P);
  } else {
    hipLaunchKernelGGL((spec_main_kernel<false>), grid, block, 0, stream, specs, mask, out,
                       (const BSParams*)nullptr);
  }
}

// Round 4
// 54.771 us; speedup vs baseline: 1.8402x; 1.8402x over previous
//
#include <hip/hip_runtime.h>
#include <stdint.h>

namespace {

constexpr int kB = 32, kS = 8, kT = 1024, kF = 128;
constexpr int kBS = kB * kS;          // 256
constexpr int kSlice = kT * kF;       // 131072 elements per (b,s)
constexpr uint32_t kSpanT = 122;      // randint(1, 123) span
constexpr uint32_t kSpanF = 15;       // randint(1, 16)  span

typedef float f32x4 __attribute__((ext_vector_type(4)));

struct BSParams {
  int ts1, te1, ts2, te2;   // time-mask intervals [s,e) (apply folded: e==s when not applied)
  int fs1, fe1, fs2, fe2;   // freq-mask intervals
  float scale;
  int apply_n;
  uint32_t kn0, kn1;        // noise key
};  // 48 bytes

__device__ __forceinline__ uint32_t rotl32(uint32_t v, int d) {
  return (v << d) | (v >> (32 - d));
}

// Threefry-2x32, 20 rounds (JAX-compatible).
__device__ __forceinline__ void tf2x32(uint32_t k0, uint32_t k1, uint32_t x0, uint32_t x1,
                                       uint32_t& o0, uint32_t& o1) {
  const uint32_t ks0 = k0, ks1 = k1, ks2 = k0 ^ k1 ^ 0x1BD11BDAu;
  x0 += ks0; x1 += ks1;
  x0 += x1; x1 = rotl32(x1, 13); x1 ^= x0;
  x0 += x1; x1 = rotl32(x1, 15); x1 ^= x0;
  x0 += x1; x1 = rotl32(x1, 26); x1 ^= x0;
  x0 += x1; x1 = rotl32(x1, 6);  x1 ^= x0;
  x0 += ks1; x1 += ks2 + 1u;
  x0 += x1; x1 = rotl32(x1, 17); x1 ^= x0;
  x0 += x1; x1 = rotl32(x1, 29); x1 ^= x0;
  x0 += x1; x1 = rotl32(x1, 16); x1 ^= x0;
  x0 += x1; x1 = rotl32(x1, 24); x1 ^= x0;
  x0 += ks2; x1 += ks0 + 2u;
  x0 += x1; x1 = rotl32(x1, 13); x1 ^= x0;
  x0 += x1; x1 = rotl32(x1, 15); x1 ^= x0;
  x0 += x1; x1 = rotl32(x1, 26); x1 ^= x0;
  x0 += x1; x1 = rotl32(x1, 6);  x1 ^= x0;
  x0 += ks0; x1 += ks1 + 3u;
  x0 += x1; x1 = rotl32(x1, 17); x1 ^= x0;
  x0 += x1; x1 = rotl32(x1, 29); x1 ^= x0;
  x0 += x1; x1 = rotl32(x1, 16); x1 ^= x0;
  x0 += x1; x1 = rotl32(x1, 24); x1 ^= x0;
  x0 += ks1; x1 += ks2 + 4u;
  x0 += x1; x1 = rotl32(x1, 13); x1 ^= x0;
  x0 += x1; x1 = rotl32(x1, 15); x1 ^= x0;
  x0 += x1; x1 = rotl32(x1, 26); x1 ^= x0;
  x0 += x1; x1 = rotl32(x1, 6);  x1 ^= x0;
  x0 += ks2; x1 += ks0 + 5u;
  o0 = x0; o1 = x1;
}

// Partitionable-mode random bits (32-bit) at flat counter i: xor of both output words.
__device__ __forceinline__ uint32_t bits32(uint32_t k0, uint32_t k1, uint32_t ctr) {
  uint32_t o0, o1;
  tf2x32(k0, k1, 0u, ctr, o0, o1);
  return o0 ^ o1;
}

// uniform [0,1) from 32 random bits, JAX-style.
__device__ __forceinline__ float u01(uint32_t bits) {
  return __uint_as_float(0x3f800000u | (bits >> 9)) - 1.0f;
}

// Fast erfinv: Giles main poly with hardware log, branchless 2-term tail.
// Tail fit err <= 0.011 over w in [5,16.6] -> <=0.001 on the final output (budget 0.113).
__device__ __forceinline__ float erfinv_fast(float x) {
  float t = fmaf(-x, x, 1.0f);                          // 1 - x^2 (fma: no cancellation)
  float w = -0.69314718f * __builtin_amdgcn_logf(t);    // -ln(1-x^2)
  float wm = w - 2.5f;
  float p = 2.81022636e-08f;
  p = fmaf(p, wm, 3.43273939e-07f);
  p = fmaf(p, wm, -3.5233877e-06f);
  p = fmaf(p, wm, -4.39150654e-06f);
  p = fmaf(p, wm, 0.00021858087f);
  p = fmaf(p, wm, -0.00125372503f);
  p = fmaf(p, wm, -0.00417768164f);
  p = fmaf(p, wm, 0.246640727f);
  p = fmaf(p, wm, 1.50140941f);
  float tail = fmaf(1.0003f, __builtin_amdgcn_sqrtf(w), -0.1623f);
  p = (w < 5.0f) ? p : tail;
  return p * x;
}

// One _axis_mask's per-(b,s) params: split(K,3) -> k1(randint),k2(uniform start),k3(apply).
__device__ void axis_params(uint32_t K0, uint32_t K1, int dim, uint32_t span, uint32_t i,
                            int& start_out, int& end_out) {
  uint32_t k10, k11, k20, k21, k30, k31, a0, a1, b0, b1;
  tf2x32(K0, K1, 0u, 0u, k10, k11);   // k1
  tf2x32(K0, K1, 0u, 1u, k20, k21);   // k2
  tf2x32(K0, K1, 0u, 2u, k30, k31);   // k3
  tf2x32(k10, k11, 0u, 0u, a0, a1);   // randint internal split
  tf2x32(k10, k11, 0u, 1u, b0, b1);
  uint32_t hi = bits32(a0, a1, i);
  uint32_t lo = bits32(b0, b1, i);
  uint32_t mult = 65536u % span;
  mult = (mult * mult) % span;
  uint32_t off = ((hi % span) * mult + (lo % span)) % span;
  int width = 1 + (int)off;
  float u = u01(bits32(k20, k21, i));
  int M = dim - width; if (M < 1) M = 1;
  int start = (int)floorf(u * (float)M);
  bool apply = u01(bits32(k30, k31, i)) > 0.35f;
  start_out = start;
  end_out = apply ? (start + width) : start;   // empty interval when not applied
}

__device__ BSParams compute_params(uint32_t i) {
  BSParams p;
  uint32_t w0, w1;
  tf2x32(0u, 42u, 0u, 0u, w0, w1); axis_params(w0, w1, kT, kSpanT, i, p.ts1, p.te1);  // kt1
  tf2x32(0u, 42u, 0u, 1u, w0, w1); axis_params(w0, w1, kT, kSpanT, i, p.ts2, p.te2);  // kt2
  tf2x32(0u, 42u, 0u, 2u, w0, w1); axis_params(w0, w1, kF, kSpanF, i, p.fs1, p.fe1);  // kf1
  tf2x32(0u, 42u, 0u, 3u, w0, w1); axis_params(w0, w1, kF, kSpanF, i, p.fs2, p.fe2);  // kf2
  tf2x32(0u, 42u, 0u, 4u, w0, w1);                                                    // kn_a
  p.apply_n = (u01(bits32(w0, w1, i)) > 0.45f) ? 1 : 0;
  tf2x32(0u, 42u, 0u, 5u, p.kn0, p.kn1);                                              // kn
  tf2x32(0u, 42u, 0u, 6u, w0, w1);                                                    // ks_a
  bool apply_s = u01(bits32(w0, w1, i)) > 0.5f;
  tf2x32(0u, 42u, 0u, 7u, w0, w1);                                                    // ks
  float su = u01(bits32(w0, w1, i));
  float sc = fmaxf(0.85f, fmaf(su, 1.15f - 0.85f, 0.85f));
  p.scale = apply_s ? sc : 1.0f;
  return p;
}

__global__ void spec_params_kernel(BSParams* __restrict__ P) {
  uint32_t i = threadIdx.x;  // 0..255 == b*8+s
  P[i] = compute_params(i);
}

// Layout: block covers 4096 elems of one (b,s) slice as 4 chunks of 1024.
// Thread handles 4 floats per chunk at (chunk*1024 + tid*4): every load/store
// instruction is lane-contiguous (16 B/lane -> 1 KiB/wave) so nt-stores write
// only full lines (no RMW amplification).
template <bool USE_WS>
__global__ __launch_bounds__(256) void spec_main_kernel(const float* __restrict__ specs,
                                                        const int* __restrict__ mask,
                                                        float* __restrict__ out,
                                                        const BSParams* __restrict__ P) {
  const int bs = blockIdx.y;                           // 0..255
  const int block_off = blockIdx.x * 4096;             // within slice
  const int tid4 = threadIdx.x * 4;
  const long slice_base = (long)bs * kSlice;

  f32x4 a[4];
  long base[4];
#pragma unroll
  for (int k = 0; k < 4; ++k) {
    base[k] = slice_base + block_off + k * 1024 + tid4;
    a[k] = *reinterpret_cast<const f32x4*>(specs + base[k]);
  }

  if (mask[bs] == 0) {  // sensor off: pure passthrough (uniform per block)
#pragma unroll
    for (int k = 0; k < 4; ++k)
      __builtin_nontemporal_store(a[k], reinterpret_cast<f32x4*>(out + base[k]));
    return;
  }

  BSParams p;
  if (USE_WS) p = P[bs]; else p = compute_params((uint32_t)bs);

  const float LO = __int_as_float(0xBF7FFFFF);   // nextafter(-1, 0)
  const float sc = p.scale;
  const bool noise = (p.apply_n != 0);

#pragma unroll
  for (int k = 0; k < 4; ++k) {
    const int off = block_off + k * 1024 + tid4;
    const int t = off >> 7;
    const int f0 = off & 127;                    // 4 elems: f in [f0, f0+4)
    const bool tm = !((t >= p.ts1) & (t < p.te1)) && !((t >= p.ts2) & (t < p.te2));
    // 4-bit keep mask over f in [f0, f0+4)
    int lo1 = min(4, max(0, p.fs1 - f0)), hi1 = min(4, max(0, p.fe1 - f0));
    int lo2 = min(4, max(0, p.fs2 - f0)), hi2 = min(4, max(0, p.fe2 - f0));
    uint32_t z1 = ((1u << hi1) - 1u) & ~((1u << lo1) - 1u);
    uint32_t z2 = ((1u << hi2) - 1u) & ~((1u << lo2) - 1u);
    const uint32_t keep = tm ? (0xFu & ~(z1 | z2)) : 0u;

    float v[4] = {a[k].x, a[k].y, a[k].z, a[k].w};
    if (noise) {   // uniform per block
      const uint32_t c0 = (uint32_t)base[k];
#pragma unroll
      for (int j = 0; j < 4; ++j) {
        float s = (keep & (1u << j)) ? v[j] : 0.0f;
        const uint32_t bits = bits32(p.kn0, p.kn1, c0 + (uint32_t)j);
        float u1 = __uint_as_float(0x3f800000u | (bits >> 9));   // [1,2)
        float x = fmaxf(LO, fmaf(u1, 2.0f, -2.0f) + LO);         // == (u1-1)*2 + LO
        s = fmaf(0.08485281374f, erfinv_fast(x), s);             // 0.06*sqrt(2)*erfinv
        s *= sc;
        v[j] = fminf(10.0f, fmaxf(-10.0f, s));
      }
    } else {
#pragma unroll
      for (int j = 0; j < 4; ++j) {
        float s = (keep & (1u << j)) ? v[j] : 0.0f;
        s *= sc;
        v[j] = fminf(10.0f, fmaxf(-10.0f, s));
      }
    }
    f32x4 r = {v[0], v[1], v[2], v[3]};
    __builtin_nontemporal_store(r, reinterpret_cast<f32x4*>(out + base[k]));
  }
}

}  // namespace

extern "C" void kernel_launch(void* const* d_in, const int* in_sizes, int n_in,
                              void* d_out, int out_size, void* d_ws, size_t ws_size,
                              hipStream_t stream) {
  const float* specs = (const float*)d_in[0];
  const int* mask = (const int*)d_in[1];
  float* out = (float*)d_out;

  dim3 grid(kSlice / 4096, kBS);  // (32, 256)
  dim3 block(256);

  if (ws_size >= sizeof(BSParams) * kBS) {
    BSParams* P = (BSParams*)d_ws;
    hipLaunchKernelGGL(spec_params_kernel, dim3(1), dim3(kBS), 0, stream, P);
    hipLaunchKernelGGL((spec_main_kernel<true>), grid, block, 0, stream, specs, mask, out, P);
  } else {
    hipLaunchKernelGGL((spec_main_kernel<false>), grid, block, 0, stream, specs, mask, out,
                       (const BSParams*)nullptr);
  }
}